// Round 10
// baseline (347.538 us; speedup 1.0000x reference)
//
#include <hip/hip_runtime.h>
#include <math.h>

// GCN 2-layer (1->8->1), collapsed + factored + dst-binned (zero global atomics
// on the accumulate paths).
//
// Math (verified):
//   deg[d]  = #edges into d; dinv = rsqrt(deg+1)            (self-loop)
//   v[i]    = dinv[i]*x[i]                                  (stored fp16)
//   acc1[d] = sum_e v[src[e]]
//   at[i]   = dinv[i]*(acc1[i] + v[i])
//   u[i]    = dinv[i] * sum_j relu(at[i]*W1[j]+b1[j])*W2[j] (stored fp16)
//   out[d]  = dinv[d]*(acc2[d] + u[d]) + b2,  acc2[d] = sum_e u[src[e]]
//
// Round-10: CHUNK 16384->8192 so k_sort fits 2 blocks/CU (round-9: 108KB LDS
// -> 1 block/CU -> 17% occupancy was the limiter; VALU fix alone gave little).
// Accepted cost: ~8 rec/bucket/block -> write amp ~2.9x (~105MB, +6us traffic).
// Record = ((dst&1023)<<20)|src (requires N <= 2^20).

typedef int vint4 __attribute__((ext_vector_type(4)));

#define HB    1024    // bucket capacity in LDS tables (>= NB)
#define STHR  512     // sort block size (8 waves)
#define CHUNK 8192    // edges per sort block
#define BSH   10      // bucket shift (1024 nodes/bucket)
#define BMASK 1023

__global__ void k_zero_gcur(int* __restrict__ gcur, int NB) {
    int i = blockIdx.x * blockDim.x + threadIdx.x;
    if (i < NB) gcur[i] = 0;
}

// ---- fused counting sort: one block per 8K-edge chunk ----
__global__ __launch_bounds__(STHR) void k_sort(const int* __restrict__ src,
                                               const int* __restrict__ dst,
                                               int E, int NB, int C,
                                               int* __restrict__ gcur,
                                               int* __restrict__ recs) {
    __shared__ int cnt[HB];            // phase A: counts; phase C: cursors
    __shared__ int off[HB + 4];        // exclusive within-block offsets
    __shared__ int res[HB];            // res2[b] = C*b + gbase[b] - off[b]
    __shared__ int part[STHR];
    __shared__ int stage[CHUNK];       // 32 KB bucket-ordered record staging
    __shared__ unsigned short s2b[CHUNK]; // 16 KB slot -> bucket

    int t = threadIdx.x;
    for (int i = t; i < NB; i += STHR) cnt[i] = 0;
    __syncthreads();

    long s0 = (long)blockIdx.x * CHUNK;
    int end = (int)min((long)CHUNK, (long)E - s0);
    const vint4* pd = reinterpret_cast<const vint4*>(dst + s0);
    const vint4* ps = reinterpret_cast<const vint4*>(src + s0);
    int n4 = end >> 2;

    // ---- phase A: bucket histogram ----
    for (int k = t; k < n4; k += STHR) {
        vint4 d = __builtin_nontemporal_load(pd + k);
        atomicAdd(&cnt[((unsigned)d.x) >> BSH], 1);
        atomicAdd(&cnt[((unsigned)d.y) >> BSH], 1);
        atomicAdd(&cnt[((unsigned)d.z) >> BSH], 1);
        atomicAdd(&cnt[((unsigned)d.w) >> BSH], 1);
    }
    for (int k = (n4 << 2) + t; k < end; k += STHR)
        atomicAdd(&cnt[((unsigned)dst[s0 + k]) >> BSH], 1);
    __syncthreads();

    // ---- phase B: block scan (2 buckets/thread) + bulk global reservation ----
    int b0 = 2 * t, b1 = 2 * t + 1;
    int c0 = (b0 < NB) ? cnt[b0] : 0;
    int c1 = (b1 < NB) ? cnt[b1] : 0;
    part[t] = c0 + c1;
    __syncthreads();
    for (int o = 1; o < STHR; o <<= 1) {
        int pv = (t >= o) ? part[t - o] : 0;
        __syncthreads();
        part[t] += pv;
        __syncthreads();
    }
    int base0 = (t > 0) ? part[t - 1] : 0;
    if (b0 < NB) {
        off[b0] = base0;
        cnt[b0] = base0;                       // cursor for phase C
        int r0 = c0 ? atomicAdd(&gcur[b0], c0) : 0;
        res[b0] = b0 * C + r0 - base0;         // res2
    }
    if (b1 < NB) {
        int o1 = base0 + c0;
        off[b1] = o1;
        cnt[b1] = o1;
        int r1 = c1 ? atomicAdd(&gcur[b1], c1) : 0;
        res[b1] = b1 * C + r1 - o1;            // res2
    }
    __syncthreads();

    // ---- phase C: place records into LDS staging (bucket-ordered) ----
    for (int k = t; k < n4; k += STHR) {
        vint4 d = __builtin_nontemporal_load(pd + k);
        vint4 s = __builtin_nontemporal_load(ps + k);
        int b, slot;
        b = ((unsigned)d.x) >> BSH; slot = atomicAdd(&cnt[b], 1);
        stage[slot] = ((d.x & BMASK) << 20) | s.x; s2b[slot] = (unsigned short)b;
        b = ((unsigned)d.y) >> BSH; slot = atomicAdd(&cnt[b], 1);
        stage[slot] = ((d.y & BMASK) << 20) | s.y; s2b[slot] = (unsigned short)b;
        b = ((unsigned)d.z) >> BSH; slot = atomicAdd(&cnt[b], 1);
        stage[slot] = ((d.z & BMASK) << 20) | s.z; s2b[slot] = (unsigned short)b;
        b = ((unsigned)d.w) >> BSH; slot = atomicAdd(&cnt[b], 1);
        stage[slot] = ((d.w & BMASK) << 20) | s.w; s2b[slot] = (unsigned short)b;
    }
    for (int k = (n4 << 2) + t; k < end; k += STHR) {
        int d = dst[s0 + k], s = src[s0 + k];
        int b = ((unsigned)d) >> BSH;
        int slot = atomicAdd(&cnt[b], 1);
        stage[slot] = ((d & BMASK) << 20) | s;
        s2b[slot] = (unsigned short)b;
    }
    __syncthreads();

    // ---- phase D: coalesced flush, direct address ----
    for (int i = t; i < end; i += STHR) {
        int b = s2b[i];
        __builtin_nontemporal_store(stage[i], recs + (long)(res[b] + i));
    }
}

// ---- per-bucket deg count -> dinv, v(fp16) ----
__global__ __launch_bounds__(512) void k_degv(const int* __restrict__ recs,
                                              const int* __restrict__ gcur, int C,
                                              const float* __restrict__ x,
                                              float* __restrict__ dinv,
                                              _Float16* __restrict__ v, int N) {
    __shared__ int c[1024];
    int t = threadIdx.x;
    c[t] = 0; c[t + 512] = 0;
    __syncthreads();
    int lo = blockIdx.x * C;
    int cnt_ = gcur[blockIdx.x];
    int n4 = cnt_ >> 2;
    const vint4* p = reinterpret_cast<const vint4*>(recs + lo);
    for (int k = t; k < n4; k += 512) {
        vint4 r = __builtin_nontemporal_load(p + k);
        atomicAdd(&c[((unsigned)r.x) >> 20], 1);
        atomicAdd(&c[((unsigned)r.y) >> 20], 1);
        atomicAdd(&c[((unsigned)r.z) >> 20], 1);
        atomicAdd(&c[((unsigned)r.w) >> 20], 1);
    }
    for (int k = (n4 << 2) + t; k < cnt_; k += 512)
        atomicAdd(&c[((unsigned)__builtin_nontemporal_load(recs + lo + k)) >> 20], 1);
    __syncthreads();
#pragma unroll
    for (int j = 0; j < 2; ++j) {
        int node = blockIdx.x * 1024 + t + 512 * j;
        if (node < N) {
            float di = rsqrtf((float)c[t + 512 * j] + 1.0f);
            dinv[node] = di;
            v[node] = (_Float16)(di * x[node]);
        }
    }
}

// ---- layer-1 gather/LDS-scatter + fused MLP -> u(fp16) ----
__global__ __launch_bounds__(512) void k_gs1(const int* __restrict__ recs,
                                             const int* __restrict__ gcur, int C,
                                             const _Float16* __restrict__ v,
                                             const float* __restrict__ dinv,
                                             const float* __restrict__ W1,
                                             const float* __restrict__ b1,
                                             const float* __restrict__ W2,
                                             _Float16* __restrict__ u, int N) {
    __shared__ float acc[1024];
    int t = threadIdx.x;
    acc[t] = 0.0f; acc[t + 512] = 0.0f;
    __syncthreads();
    int lo = blockIdx.x * C;
    int cnt_ = gcur[blockIdx.x];
    int n4 = cnt_ >> 2;
    const vint4* p = reinterpret_cast<const vint4*>(recs + lo);
    for (int k = t; k < n4; k += 512) {
        vint4 r = __builtin_nontemporal_load(p + k);
        float v0 = (float)v[r.x & 0xFFFFF], v1 = (float)v[r.y & 0xFFFFF];
        float v2 = (float)v[r.z & 0xFFFFF], v3 = (float)v[r.w & 0xFFFFF];
        atomicAdd(&acc[((unsigned)r.x) >> 20], v0);
        atomicAdd(&acc[((unsigned)r.y) >> 20], v1);
        atomicAdd(&acc[((unsigned)r.z) >> 20], v2);
        atomicAdd(&acc[((unsigned)r.w) >> 20], v3);
    }
    for (int k = (n4 << 2) + t; k < cnt_; k += 512) {
        int r = __builtin_nontemporal_load(recs + lo + k);
        atomicAdd(&acc[((unsigned)r) >> 20], (float)v[r & 0xFFFFF]);
    }
    __syncthreads();
#pragma unroll
    for (int j = 0; j < 2; ++j) {
        int node = blockIdx.x * 1024 + t + 512 * j;
        if (node < N) {
            float di = dinv[node];
            float at = di * (acc[t + 512 * j] + (float)v[node]);
            float s = 0.0f;
#pragma unroll
            for (int jj = 0; jj < 8; ++jj)
                s += fmaxf(at * W1[jj] + b1[jj], 0.0f) * W2[jj];
            u[node] = (_Float16)(di * s);
        }
    }
}

// ---- layer-2 gather/LDS-scatter + fused finalize -> out ----
__global__ __launch_bounds__(512) void k_gs2(const int* __restrict__ recs,
                                             const int* __restrict__ gcur, int C,
                                             const _Float16* __restrict__ u,
                                             const float* __restrict__ dinv,
                                             const float* __restrict__ b2,
                                             float* __restrict__ out, int N) {
    __shared__ float acc[1024];
    int t = threadIdx.x;
    acc[t] = 0.0f; acc[t + 512] = 0.0f;
    __syncthreads();
    int lo = blockIdx.x * C;
    int cnt_ = gcur[blockIdx.x];
    int n4 = cnt_ >> 2;
    const vint4* p = reinterpret_cast<const vint4*>(recs + lo);
    for (int k = t; k < n4; k += 512) {
        vint4 r = __builtin_nontemporal_load(p + k);
        float v0 = (float)u[r.x & 0xFFFFF], v1 = (float)u[r.y & 0xFFFFF];
        float v2 = (float)u[r.z & 0xFFFFF], v3 = (float)u[r.w & 0xFFFFF];
        atomicAdd(&acc[((unsigned)r.x) >> 20], v0);
        atomicAdd(&acc[((unsigned)r.y) >> 20], v1);
        atomicAdd(&acc[((unsigned)r.z) >> 20], v2);
        atomicAdd(&acc[((unsigned)r.w) >> 20], v3);
    }
    for (int k = (n4 << 2) + t; k < cnt_; k += 512) {
        int r = __builtin_nontemporal_load(recs + lo + k);
        atomicAdd(&acc[((unsigned)r) >> 20], (float)u[r & 0xFFFFF]);
    }
    __syncthreads();
#pragma unroll
    for (int j = 0; j < 2; ++j) {
        int node = blockIdx.x * 1024 + t + 512 * j;
        if (node < N)
            out[node] = dinv[node] * (acc[t + 512 * j] + (float)u[node]) + b2[0];
    }
}

extern "C" void kernel_launch(void* const* d_in, const int* in_sizes, int n_in,
                              void* d_out, int out_size, void* d_ws, size_t ws_size,
                              hipStream_t stream) {
    const float* x  = (const float*)d_in[0];
    const int*   ei = (const int*)d_in[1];   // [2, E] int32
    const float* W1 = (const float*)d_in[2];
    const float* b1 = (const float*)d_in[3];
    const float* W2 = (const float*)d_in[4];
    const float* b2 = (const float*)d_in[5];
    float* out = (float*)d_out;

    int N = in_sizes[0];
    int E = in_sizes[1] / 2;
    const int* src = ei;
    const int* dst = ei + E;

    int NB = (N + BMASK) >> BSH;             // 1024-node buckets (<= 1024 for N<=2^20)

    // fixed bucket capacity: avg + 8 sigma (Poisson), rounded to 64
    int avg = E / NB;
    int C = avg + 8 * (int)sqrt((double)avg) + 64;
    C = (C + 63) & ~63;
    size_t fixed = sizeof(float) * (size_t)N + sizeof(_Float16) * 2ul * N
                 + sizeof(int) * (size_t)NB;
    size_t maxC = (ws_size - fixed) / (sizeof(int) * (size_t)NB);
    if ((size_t)C > maxC) C = (int)maxC;

    char* w = (char*)d_ws;
    float*    dinv = (float*)w;     w += sizeof(float) * (size_t)N;
    _Float16* v    = (_Float16*)w;  w += sizeof(_Float16) * (size_t)N;
    _Float16* u    = (_Float16*)w;  w += sizeof(_Float16) * (size_t)N;
    int*      gcur = (int*)w;       w += sizeof(int) * (size_t)NB;
    int*      recs = (int*)w;       // NB * C ints

    int NBLK = (E + CHUNK - 1) / CHUNK;

    k_zero_gcur<<<(NB + 255) / 256, 256, 0, stream>>>(gcur, NB);
    k_sort<<<NBLK, STHR, 0, stream>>>(src, dst, E, NB, C, gcur, recs);
    k_degv<<<NB, 512, 0, stream>>>(recs, gcur, C, x, dinv, v, N);
    k_gs1 <<<NB, 512, 0, stream>>>(recs, gcur, C, v, dinv, W1, b1, W2, u, N);
    k_gs2 <<<NB, 512, 0, stream>>>(recs, gcur, C, u, dinv, b2, out, N);
}